// Round 11
// baseline (1250.670 us; speedup 1.0000x reference)
//
#include <hip/hip_runtime.h>

// Net_4544075399853: x->20 linear, LSTMCell(20,20), 20->1 linear; B=8192, T=2048, fp32.
// R16: 2-units-per-lane layout — 6 rows/wave (was 3), same per-wave issue.
//  - R15 accounting: per-wave VALU issue I ~289cy/step is nearly layout-
//    invariant; rows/wave is the amortization lever. New mapping: lane =
//    (row r = lane/10, units m=lane%10 and m+10). Per-wave stream: 80 gate
//    dot2 + 10 out dot2 + 16 trans + act/misc ~= 340cy for 6 rows = 57cy/row
//    (R14: 96cy/row). Weights stay register-feasible: 80 VGPRs fp16.
//  - Exchange unchanged at 4 DS ops: LDS row = 10 u32, slot q = (h_q, h_{q+10})
//    packed fp16 pair. Each lane writes its 2 units as ONE b32; readers use
//    pairs directly with k-PERMUTED weight pairs (dot is order-invariant).
//  - Out: dedicated 10-dot2 accumulator in the uniform stream; W2 nonzero only
//    on out lanes: rows 0-3 -> spare lanes 60-63 (they read their out row's h),
//    rows 4,5 -> lanes 40,50 (their own row). o consumes h_t -> out[t-1],
//    same timing trick as before. Epilogue emits out[T-1].
//  - Grid 1366 waves: 342 SIMDs x2 (critical, wall ~2I ~680cy/step ~580us) +
//    682 x1 (finish early). NOT R9b's mistake (that doubled per-wave issue;
//    this doubles rows at constant issue).
//  - Unchanged: fp16 dot2 GEMV fp32-accum, cs fp32 lane-local, fused-rcp
//    activations, barrier-free single-buffer LDS (single-wave WG), x float4
//    prefetched 1 iter ahead, packed float4 out stores, setprio tail hint.

#define HID 20
#define LPR 10     // lanes per row
#define RPW 6      // rows per wave
#define NTHREADS 64
#define L2E 1.4426950408889634f

typedef _Float16 v2h __attribute__((ext_vector_type(2)));

__device__ __forceinline__ float exp2_hw(float v) { return __builtin_amdgcn_exp2f(v); }
__device__ __forceinline__ float rcp_hw(float v)  { return __builtin_amdgcn_rcpf(v); }

// gs = log2e * g   -> sigmoid(g)   (f-gate)
__device__ __forceinline__ float sig_s(float gs) {
    return rcp_hw(1.0f + exp2_hw(-gs));
}

// fp16 pair dot with fp32 accumulate: acc += w.x*h.x + w.y*h.y
__device__ __forceinline__ float dot2(v2h w, v2h h, float acc) {
#if __has_builtin(__builtin_amdgcn_fdot2)
    return __builtin_amdgcn_fdot2(w, h, acc, false);
#else
    asm("v_dot2_f32_f16 %0, %1, %2, %0" : "+v"(acc) : "v"(w), "v"(h));
    return acc;
#endif
}

__device__ __forceinline__ v2h u2h(unsigned u) {
    v2h r; __builtin_memcpy(&r, &u, 4); return r;
}
__device__ __forceinline__ unsigned h2u(v2h h) {
    unsigned r; __builtin_memcpy(&r, &h, 4); return r;
}

__global__ __attribute__((amdgpu_flat_work_group_size(NTHREADS, NTHREADS),
                          amdgpu_waves_per_eu(2, 2)))
void lstm_wave(
        const float* __restrict__ x,     // [B, T]
        const float* __restrict__ W1,    // [20]
        const float* __restrict__ b1,    // [20]
        const float* __restrict__ W_ih,  // [80, 20]
        const float* __restrict__ W_hh,  // [80, 20]
        const float* __restrict__ b_ih,  // [80]
        const float* __restrict__ b_hh,  // [80]
        const float* __restrict__ W2,    // [20]
        const float* __restrict__ b2,    // [1]
        float* __restrict__ out,         // [B, T]
        const int B, const int T)
{
    const int lane = threadIdx.x;
    const int r    = lane / LPR;          // 0..6 (6 = spare lanes 60-63)
    const int mlo  = lane % LPR;          // 0..9 (0..3 for spares)
    const bool gatelane = (r < RPW);
    const int rslot = gatelane ? r : (lane - 60);   // LDS row this lane READS

    // out assignment: rows 0-3 -> lanes 60-63; row 4 -> lane 40; row 5 -> lane 50
    int outr = -1;
    if (lane >= 60)      outr = lane - 60;
    else if (lane == 40) outr = 4;
    else if (lane == 50) outr = 5;
    const bool has_out = (outr >= 0);

    const long rowbase = (long)blockIdx.x * RPW;
    const long xr   = rowbase + rslot;
    const long arow = (xr < B) ? xr : (B - 1);           // x address (clamped)
    const long orw  = has_out ? (rowbase + outr) : 0;
    const long oarw = (orw < B) ? orw : (B - 1);
    const bool ovalid = has_out && (orw < B);

    // LDS: [7 rows (6 + trash for spares)][12 u32] (10 used; stride 48B, 16-aligned)
    __shared__ __align__(16) unsigned hbuf[RPW + 1][12];

    // ---- per-lane parameters ----
    float u[4][2], v[4][2];       // a-init: a = fma(xv, u, v), exp2-domain scaled
    v2h   whh[4][2][LPR];         // [gate][unit lo/hi][q], pair = (k=q, k=q+10)
    v2h   w2[LPR];                // out weights (nonzero on out lanes only)
    float ob = 0.f;               // out bias

    if (gatelane) {
#pragma unroll
        for (int g = 0; g < 4; ++g) {
            const float s = (g == 2) ? (2.0f * L2E) : L2E;
#pragma unroll
            for (int un = 0; un < 2; ++un) {
                const int j = g * HID + mlo + un * 10;
                float uu = 0.f, vv = 0.f;
#pragma unroll
                for (int k = 0; k < HID; ++k) {
                    const float wi = W_ih[j * HID + k];
                    uu += wi * W1[k];
                    vv += wi * b1[k];
                }
                u[g][un] = s * uu;
                v[g][un] = s * (vv + b_ih[j] + b_hh[j]);
#pragma unroll
                for (int q = 0; q < LPR; ++q) {
                    v2h w;
                    w.x = (_Float16)(s * W_hh[j * HID + q]);
                    w.y = (_Float16)(s * W_hh[j * HID + q + 10]);
                    whh[g][un][q] = w;
                }
            }
        }
    } else {
#pragma unroll
        for (int g = 0; g < 4; ++g)
#pragma unroll
            for (int un = 0; un < 2; ++un) {
                u[g][un] = 0.f; v[g][un] = 0.f;
#pragma unroll
                for (int q = 0; q < LPR; ++q) whh[g][un][q] = (v2h)(_Float16)0;
            }
    }
    if (has_out) {
#pragma unroll
        for (int q = 0; q < LPR; ++q) {
            v2h w;
            w.x = (_Float16)W2[q];
            w.y = (_Float16)W2[q + 10];
            w2[q] = w;
        }
        ob = b2[0];
    } else {
#pragma unroll
        for (int q = 0; q < LPR; ++q) w2[q] = (v2h)(_Float16)0;
    }

    // Opaque defs: prevent remat of the weight loads into the loop.
#pragma unroll
    for (int g = 0; g < 4; ++g)
#pragma unroll
        for (int un = 0; un < 2; ++un)
#pragma unroll
            for (int q = 0; q < LPR; ++q)
                asm volatile("" : "+v"(whh[g][un][q]));
#pragma unroll
    for (int q = 0; q < LPR; ++q) asm volatile("" : "+v"(w2[q]));

    float csL = 0.f, csH = 0.f;   // c (2*log2e-scaled), fp32, lane-local

    // zero the whole buffer (84 u32)
    ((unsigned*)hbuf)[lane] = 0u;
    if (lane < 20) ((unsigned*)hbuf)[lane + 64] = 0u;
    // NOTE: no __syncthreads anywhere — single-wave workgroup, DS ops are
    // executed in wave program order by the LDS pipe.

    const float* __restrict__ xrow = x   + arow * T;
    float* __restrict__       orow = out + oarw * T;

    const uint4* __restrict__ rdp4 = (const uint4*)&hbuf[rslot][0];
    const uint2* __restrict__ rdp2 = (const uint2*)&hbuf[rslot][8];
    unsigned* __restrict__    wrp  = &hbuf[r][mlo];

    // h_t as 10 packed fp16 pairs, pair q = (h_q, h_{q+10}); h_0 = 0
    v2h hp[LPR];
#pragma unroll
    for (int q = 0; q < LPR; ++q) hp[q] = (v2h)(_Float16)0;

    float4 xq = *(const float4*)&xrow[0];   // x[t .. t+3]
    float4 xq_next;
    float4 obuf = make_float4(0.f, 0.f, 0.f, 0.f);  // out[t-4 .. t-1], comp = idx&3

// fused-rcp activations for one unit; updates CS, yields h
#define UNIT_ACT(AI, AF, AG, AO, CS, HOUT)                                      \
    {                                                                           \
        const float fg  = sig_s(AF);                                            \
        const float e0i = exp2_hw(-(AI));                                       \
        const float e2  = exp2_hw(AG);                                          \
        const float P1  = (1.0f + e0i) * (1.0f + e2);                           \
        const float igg = (2.0f * L2E) * (e2 - 1.0f) * rcp_hw(P1);              \
        CS = fg * CS + igg;                                                     \
        const float e3i = exp2_hw(-(AO));                                       \
        const float ec  = exp2_hw(CS);                                          \
        const float P2  = (1.0f + e3i) * (1.0f + ec);                           \
        HOUT = (ec - 1.0f) * rcp_hw(P2);                                        \
    }

// One LSTM step: 8 gate accums (4 gates x 2 units) + 1 out accum, 90 dot2,
// activations, pack h pair -> 1 ds_write_b32, then re-read the row (b128+b128+b64).
#define BODY(XV, OSLOT)                                                         \
    {                                                                           \
        const float xv = (XV);                                                  \
        float a00 = fmaf(xv, u[0][0], v[0][0]);                                 \
        float a01 = fmaf(xv, u[0][1], v[0][1]);                                 \
        float a10 = fmaf(xv, u[1][0], v[1][0]);                                 \
        float a11 = fmaf(xv, u[1][1], v[1][1]);                                 \
        float a20 = fmaf(xv, u[2][0], v[2][0]);                                 \
        float a21 = fmaf(xv, u[2][1], v[2][1]);                                 \
        float a30 = fmaf(xv, u[3][0], v[3][0]);                                 \
        float a31 = fmaf(xv, u[3][1], v[3][1]);                                 \
        float o   = ob;                                                         \
        _Pragma("unroll")                                                       \
        for (int q = 0; q < LPR; ++q) {                                         \
            const v2h hq = hp[q];                                               \
            a00 = dot2(whh[0][0][q], hq, a00);                                  \
            a01 = dot2(whh[0][1][q], hq, a01);                                  \
            a10 = dot2(whh[1][0][q], hq, a10);                                  \
            a11 = dot2(whh[1][1][q], hq, a11);                                  \
            a20 = dot2(whh[2][0][q], hq, a20);                                  \
            a21 = dot2(whh[2][1][q], hq, a21);                                  \
            a30 = dot2(whh[3][0][q], hq, a30);                                  \
            a31 = dot2(whh[3][1][q], hq, a31);                                  \
            o   = dot2(w2[q],        hq, o);                                    \
        }                                                                       \
        OSLOT = o;                                                              \
        __builtin_amdgcn_s_setprio(1);                                          \
        float hL, hH;                                                           \
        UNIT_ACT(a00, a10, a20, a30, csL, hL)                                   \
        UNIT_ACT(a01, a11, a21, a31, csH, hH)                                   \
        v2h hpk; hpk.x = (_Float16)hL; hpk.y = (_Float16)hH;                    \
        *wrp = h2u(hpk);                                                        \
        const uint4 Ra = rdp4[0];                                               \
        const uint4 Rb = rdp4[1];                                               \
        const uint2 Rc = *rdp2;                                                 \
        __builtin_amdgcn_s_setprio(0);                                          \
        hp[0] = u2h(Ra.x); hp[1] = u2h(Ra.y); hp[2] = u2h(Ra.z);                \
        hp[3] = u2h(Ra.w); hp[4] = u2h(Rb.x); hp[5] = u2h(Rb.y);                \
        hp[6] = u2h(Rb.z); hp[7] = u2h(Rb.w); hp[8] = u2h(Rc.x);                \
        hp[9] = u2h(Rc.y);                                                      \
    }

    for (int t = 0; t < T; t += 4) {
        // prefetch next iteration's x a full 4 steps ahead (clamped on last iter)
        const int tp = (t + 4 < T) ? (t + 4) : t;
        xq_next = *(const float4*)&xrow[tp];

        BODY(xq.x, obuf.w)                       // step t   -> out[t-1] (comp 3)
        if (t >= 4 && ovalid) *(float4*)&orow[t - 4] = obuf;   // out[t-4..t-1]
        BODY(xq.y, obuf.x)                       // step t+1 -> out[t]   (comp 0)
        BODY(xq.z, obuf.y)                       // step t+2 -> out[t+1] (comp 1)
        BODY(xq.w, obuf.z)                       // step t+3 -> out[t+2] (comp 2)

        xq = xq_next;
    }

    // epilogue: out[T-1] = b2 + W2 @ h_T ; h_T is in hp (reads issued by last body)
    {
        float o = ob;
#pragma unroll
        for (int q = 0; q < LPR; ++q)
            o = dot2(w2[q], hp[q], o);
        obuf.w = o;                                   // out[T-1] (comp 3)
        if (ovalid) *(float4*)&orow[T - 4] = obuf;    // out[T-4..T-1]
    }
#undef BODY
#undef UNIT_ACT
}

extern "C" void kernel_launch(void* const* d_in, const int* in_sizes, int n_in,
                              void* d_out, int out_size, void* d_ws, size_t ws_size,
                              hipStream_t stream) {
    (void)n_in; (void)d_ws; (void)ws_size; (void)out_size;
    const float* x    = (const float*)d_in[0];
    const float* W1   = (const float*)d_in[1];
    const float* b1   = (const float*)d_in[2];
    const float* W_ih = (const float*)d_in[3];
    const float* W_hh = (const float*)d_in[4];
    const float* b_ih = (const float*)d_in[5];
    const float* b_hh = (const float*)d_in[6];
    const float* W2   = (const float*)d_in[7];
    const float* b2   = (const float*)d_in[8];
    float* out        = (float*)d_out;

    const int B = 8192;
    const int T = in_sizes[0] / B;  // 2048 (divisible by 4)
    const int grid = (B + RPW - 1) / RPW;  // 1366 single-wave blocks, 6 rows each

    lstm_wave<<<grid, NTHREADS, 0, stream>>>(x, W1, b1, W_ih, W_hh, b_ih, b_hh, W2, b2, out, B, T);
}